// Round 6
// baseline (469.048 us; speedup 1.0000x reference)
//
#include <hip/hip_runtime.h>
#include <hip/hip_cooperative_groups.h>

namespace cg = cooperative_groups;

#define F 128
#define NEG_SLOPE 0.01f
#define NPB 512      // nodes per bucket (1<<9)
#define PMAX 256     // max buckets; nP = ceil(N/512) = 196
#define GMAX 256     // padded hcount row length (max grid)
#define BB 8192      // edges per block slice
#define CAP 9216     // csr LDS staging capacity (avg 8163, sd~90; spill path correct)

typedef _Float16 half8_t __attribute__((ext_vector_type(8)));
typedef float f32x4 __attribute__((ext_vector_type(4)));

// ---------------- CSR build: ONE cooperative kernel ----------------
// Replaces zero+hist+scan+bin+csr. Grid (196) <= 256 CUs -> co-resident;
// per-block LDS histogram persists across grid.sync(), so dst is
// histogrammed once (not twice) and bcnt/bbase/bcur global arrays are
// gone. Edge records pack to 4B: (dst_local<<17)|src  (src < 2^17).
// Phase A: local hist (+ W-convert on blocks 0..15) -> hcount[bucket][blk]
// Phase B: per-block prefix over hcount -> deterministic binned write
// Phase C: block b == bucket b -> exact CSR + offs + dis

__global__ __launch_bounds__(512) void csr_coop(const int* __restrict__ src,
                                                const int* __restrict__ dst,
                                                int E,
                                                const float* __restrict__ W1,
                                                const float* __restrict__ W2,
                                                _Float16* __restrict__ W1h,
                                                _Float16* __restrict__ W2h,
                                                int* __restrict__ hcount,
                                                int* __restrict__ binned,
                                                int* __restrict__ srcs,
                                                int* __restrict__ offs,
                                                float* __restrict__ dis,
                                                int N, int nP) {
    __shared__ int hist[PMAX];
    __shared__ int lbase[PMAX];
    __shared__ int gbase[PMAX];
    __shared__ int curA[PMAX];
    __shared__ int sa[PMAX];
    __shared__ int buf2[BB];
    __shared__ unsigned char b8[BB];
    __shared__ int cnt[NPB];
    __shared__ int tmp[NPB];
    __shared__ int cur2[NPB];
    __shared__ int bufC[CAP];
    __shared__ int ebase_s, count_s;

    cg::grid_group grid = cg::this_grid();
    const int t = threadIdx.x;
    const int b = blockIdx.x;
    const int nblk = gridDim.x;
    const int base = b * BB;
    int myE = E - base; if (myE > BB) myE = BB; if (myE < 0) myE = 0;

    // ---- Phase A: weight convert (blocks 0..15) + local histogram ----
    if (b < 16) {
        int i = b * 512 + t;                  // 0 .. 8191
        const int n4 = F * F / 4;
        const float* in = (i < n4) ? W1 : W2;
        _Float16* outw = (i < n4) ? W1h : W2h;
        int j = (i < n4) ? i : i - n4;
        float4 v = ((const float4*)in)[j];
        half8_t hx;  // only low 4 used
        hx[0] = (_Float16)v.x; hx[1] = (_Float16)v.y;
        hx[2] = (_Float16)v.z; hx[3] = (_Float16)v.w;
        *(int2*)&((_Float16*)outw)[j * 4] = *(int2*)&hx;
    }
    if (t < PMAX) hist[t] = 0;
    __syncthreads();
    for (int i = t; i < myE; i += 512)
        atomicAdd(&hist[dst[base + i] >> 9], 1);
    __syncthreads();
    if (t < PMAX) hcount[t * GMAX + b] = hist[t];
    __threadfence();
    grid.sync();

    // ---- Phase B: bases from hcount, reorder, coalesced binned write ----
    int tot_v = 0, pfx_v = 0;
    if (t < PMAX) {
        const int* row = hcount + t * GMAX;
        for (int bl = 0; bl < nblk; ++bl) {
            int v = row[bl];
            tot_v += v;
            pfx_v += (bl < b) ? v : 0;
        }
    }
    // scan 1: global bucket totals -> exclusive bucket base
    if (t < PMAX) sa[t] = tot_v;
    __syncthreads();
    int run = tot_v;
    for (int off = 1; off < PMAX; off <<= 1) {
        int add = (t < PMAX && t >= off) ? sa[t - off] : 0;
        __syncthreads();
        if (t < PMAX) { run += add; sa[t] = run; }
        __syncthreads();
    }
    int gexc = run - tot_v;
    if (t < PMAX) gbase[t] = gexc + pfx_v;
    if (t == b) { ebase_s = gexc; count_s = tot_v; }
    __syncthreads();
    // scan 2: local hist -> lbase/curA
    int lv = (t < PMAX) ? hist[t] : 0;
    if (t < PMAX) sa[t] = lv;
    __syncthreads();
    int run2 = lv;
    for (int off = 1; off < PMAX; off <<= 1) {
        int add = (t < PMAX && t >= off) ? sa[t - off] : 0;
        __syncthreads();
        if (t < PMAX) { run2 += add; sa[t] = run2; }
        __syncthreads();
    }
    if (t < PMAX) { lbase[t] = run2 - lv; curA[t] = run2 - lv; }
    __syncthreads();
    // reorder into LDS, bucket-contiguous
    for (int i = t; i < myE; i += 512) {
        int d = dst[base + i], s = src[base + i];
        int bk = d >> 9;
        int lp = atomicAdd(&curA[bk], 1);
        buf2[lp] = ((d & (NPB - 1)) << 17) | s;
        b8[lp] = (unsigned char)bk;
    }
    __syncthreads();
    for (int j = t; j < myE; j += 512) {
        int bk = b8[j];
        binned[gbase[bk] + (j - lbase[bk])] = buf2[j];
    }
    __threadfence();
    grid.sync();

    // ---- Phase C: block b == bucket b -> CSR + offs + dis ----
    if (b >= nP) return;
    int ebase = ebase_s;
    int count = count_s;
    int lo = b << 9;
    cnt[t] = 0;
    __syncthreads();
    for (int j = t; j < count; j += 512)
        atomicAdd(&cnt[binned[ebase + j] >> 17], 1);
    __syncthreads();
    int v = cnt[t];
    int run3 = v;
    tmp[t] = v;
    __syncthreads();
    for (int off = 1; off < NPB; off <<= 1) {
        int add = (t >= off) ? tmp[t - off] : 0;
        __syncthreads();
        run3 += add;
        tmp[t] = run3;
        __syncthreads();
    }
    int excl = run3 - v;
    cur2[t] = excl;
    int node = lo + t;
    if (node < N) {
        offs[node] = ebase + excl;
        dis[node] = rsqrtf((float)v + 1.0f);
    }
    __syncthreads();
    for (int j = t; j < count; j += 512) {
        int rec = binned[ebase + j];
        int pos = atomicAdd(&cur2[rec >> 17], 1);
        int s = rec & 0x1FFFF;
        if (pos < CAP) bufC[pos] = s; else srcs[ebase + pos] = s;
    }
    __syncthreads();
    int lim = count < CAP ? count : CAP;
    for (int j = t; j < lim; j += 512)
        srcs[ebase + j] = bufC[j];
}

// ---------------- GEMM: out = (A @ W.T) * dis[row] via f16 MFMA ----------------
// Layouts: A[m=lane&15][k=quad*8+j]; B[n=lane&15][k=quad*8+j] (=W[n][k]);
// C/D: col=lane&15, row=quad*4+reg.
// Epilogue scales row r by dis[r]: downstream aggregation then needs no
// per-edge dis[src] gather.

__device__ __forceinline__ void gemm_core(const half8_t afrag[4],
                                          const _Float16* __restrict__ Wh,
                                          const float* __restrict__ dis,
                                          int tile, int m, int quad,
                                          _Float16* __restrict__ orow) {
    f32x4 acc[8];
#pragma unroll
    for (int tt = 0; tt < 8; ++tt) acc[tt] = (f32x4){0.f, 0.f, 0.f, 0.f};
#pragma unroll
    for (int c = 0; c < 4; ++c) {
#pragma unroll
        for (int tt = 0; tt < 8; ++tt) {
            half8_t bfrag = *(const half8_t*)&Wh[(tt * 16 + m) * F + c * 32 + quad * 8];
            acc[tt] = __builtin_amdgcn_mfma_f32_16x16x32_f16(afrag[c], bfrag, acc[tt],
                                                             0, 0, 0);
        }
    }
    float d[4];
#pragma unroll
    for (int r = 0; r < 4; ++r) d[r] = dis[tile * 16 + quad * 4 + r];
#pragma unroll
    for (int tt = 0; tt < 8; ++tt)
#pragma unroll
        for (int r = 0; r < 4; ++r)
            orow[(quad * 4 + r) * F + tt * 16 + m] = (_Float16)(acc[tt][r] * d[r]);
}

__global__ __launch_bounds__(256) void gemm_a32(const float* __restrict__ A,
                                                const _Float16* __restrict__ Wh,
                                                const float* __restrict__ dis,
                                                _Float16* __restrict__ out,
                                                int ntiles) {
    int wave = threadIdx.x >> 6;
    int lane = threadIdx.x & 63;
    int tile = blockIdx.x * 4 + wave;
    if (tile >= ntiles) return;
    int m = lane & 15, quad = lane >> 4;
    const float* arow = A + (size_t)tile * 16 * F;
    half8_t afrag[4];
#pragma unroll
    for (int c = 0; c < 4; ++c) {
        float4 t0 = *(const float4*)&arow[m * F + c * 32 + quad * 8];
        float4 t1 = *(const float4*)&arow[m * F + c * 32 + quad * 8 + 4];
        afrag[c][0] = (_Float16)t0.x; afrag[c][1] = (_Float16)t0.y;
        afrag[c][2] = (_Float16)t0.z; afrag[c][3] = (_Float16)t0.w;
        afrag[c][4] = (_Float16)t1.x; afrag[c][5] = (_Float16)t1.y;
        afrag[c][6] = (_Float16)t1.z; afrag[c][7] = (_Float16)t1.w;
    }
    gemm_core(afrag, Wh, dis, tile, m, quad, out + (size_t)tile * 16 * F);
}

__global__ __launch_bounds__(256) void gemm_a16(const _Float16* __restrict__ A,
                                                const _Float16* __restrict__ Wh,
                                                const float* __restrict__ dis,
                                                _Float16* __restrict__ out,
                                                int ntiles) {
    int wave = threadIdx.x >> 6;
    int lane = threadIdx.x & 63;
    int tile = blockIdx.x * 4 + wave;
    if (tile >= ntiles) return;
    int m = lane & 15, quad = lane >> 4;
    const _Float16* arow = A + (size_t)tile * 16 * F;
    half8_t afrag[4];
#pragma unroll
    for (int c = 0; c < 4; ++c)
        afrag[c] = *(const half8_t*)&arow[m * F + c * 32 + quad * 8];
    gemm_core(afrag, Wh, dis, tile, m, quad, out + (size_t)tile * 16 * F);
}

// ---------------- aggregation ----------------
// One wave per node; 16 lanes x half8 cover one 256B row; 4 edge groups
// x 2 edges in flight with next chunk's src indices software-pipelined
// (best-known structure from r2/r5; agg is at a random-gather equilibrium
// insensitive to ILP widening / persistent waves).
// Self-row/dis/bias hoisted BEFORE the gather so their latency hides.
// Rows pre-scaled by dis[src] in the GEMM epilogue -> edge weight is a
// {0,1} validity mask; self term = di*h'[node]; out = di*(sum+h'[node])+b.

#define AGG_BODY(H8)                                                           \
    int node = blockIdx.x * 4 + (threadIdx.x >> 6);                            \
    int lane = threadIdx.x & 63;                                               \
    if (node >= n) return;                                                     \
    int g = lane >> 4;                                                         \
    int fo = lane & 15;                                                        \
    int beg = offs[node];                                                      \
    int end = (node + 1 < n) ? offs[node + 1] : E;                             \
    float di = dis[node];                                                      \
    half8_t hv = H8[(size_t)node * 16 + fo];                                   \
    float4 b0 = ((const float4*)bias)[fo * 2];                                 \
    float4 b1v = ((const float4*)bias)[fo * 2 + 1];                            \
    float acc[8];                                                              \
    _Pragma("unroll") for (int j = 0; j < 8; ++j) acc[j] = 0.f;                \
    if (beg < end) {                                                           \
        int i0 = beg + g, i1 = beg + 4 + g;                                    \
        int s0 = srcs[i0 < end ? i0 : beg];                                    \
        int s1 = srcs[i1 < end ? i1 : beg];                                    \
        float w0 = (i0 < end) ? 1.f : 0.f;                                     \
        float w1 = (i1 < end) ? 1.f : 0.f;                                     \
        for (int e = beg; e < end; e += 8) {                                   \
            int ns0 = s0, ns1 = s1;                                            \
            float nw0 = 0.f, nw1 = 0.f;                                        \
            if (e + 8 < end) {                                                 \
                int j0 = e + 8 + g, j1 = e + 12 + g;                           \
                ns0 = srcs[j0 < end ? j0 : beg];                               \
                ns1 = srcs[j1 < end ? j1 : beg];                               \
                nw0 = (j0 < end) ? 1.f : 0.f;                                  \
                nw1 = (j1 < end) ? 1.f : 0.f;                                  \
            }                                                                  \
            half8_t a0 = H8[(size_t)s0 * 16 + fo];                             \
            half8_t a1 = H8[(size_t)s1 * 16 + fo];                             \
            _Pragma("unroll") for (int j = 0; j < 8; ++j)                      \
                acc[j] += w0 * (float)a0[j] + w1 * (float)a1[j];               \
            s0 = ns0; s1 = ns1; w0 = nw0; w1 = nw1;                            \
        }                                                                      \
    }                                                                          \
    _Pragma("unroll") for (int j = 0; j < 8; ++j) {                            \
        acc[j] += __shfl_xor(acc[j], 16);                                      \
        acc[j] += __shfl_xor(acc[j], 32);                                      \
    }                                                                          \
    if (lane >= 16) return;                                                    \
    acc[0] = di * (acc[0] + (float)hv[0]) + b0.x;                              \
    acc[1] = di * (acc[1] + (float)hv[1]) + b0.y;                              \
    acc[2] = di * (acc[2] + (float)hv[2]) + b0.z;                              \
    acc[3] = di * (acc[3] + (float)hv[3]) + b0.w;                              \
    acc[4] = di * (acc[4] + (float)hv[4]) + b1v.x;                             \
    acc[5] = di * (acc[5] + (float)hv[5]) + b1v.y;                             \
    acc[6] = di * (acc[6] + (float)hv[6]) + b1v.z;                             \
    acc[7] = di * (acc[7] + (float)hv[7]) + b1v.w;                             \
    _Pragma("unroll") for (int j = 0; j < 8; ++j)                              \
        acc[j] = (acc[j] > 0.f) ? acc[j] : acc[j] * NEG_SLOPE;

__global__ __launch_bounds__(256) void agg_to_h(const half8_t* __restrict__ h8,
                                                const float* __restrict__ dis,
                                                const float* __restrict__ bias,
                                                const int* __restrict__ srcs,
                                                const int* __restrict__ offs,
                                                half8_t* __restrict__ out,
                                                int n, int E) {
    AGG_BODY(h8)
    half8_t o;
#pragma unroll
    for (int j = 0; j < 8; ++j) o[j] = (_Float16)acc[j];
    out[(size_t)node * 16 + fo] = o;
}

__global__ __launch_bounds__(256) void agg_to_f(const half8_t* __restrict__ h8,
                                                const float* __restrict__ dis,
                                                const float* __restrict__ bias,
                                                const int* __restrict__ srcs,
                                                const int* __restrict__ offs,
                                                float* __restrict__ out,
                                                int n, int E) {
    AGG_BODY(h8)
    float4 o0 = make_float4(acc[0], acc[1], acc[2], acc[3]);
    float4 o1 = make_float4(acc[4], acc[5], acc[6], acc[7]);
    ((float4*)out)[(size_t)node * 32 + fo * 2] = o0;
    ((float4*)out)[(size_t)node * 32 + fo * 2 + 1] = o1;
}

// ---------------- launch ----------------

static inline size_t alup(size_t x) { return (x + 255) & ~(size_t)255; }

extern "C" void kernel_launch(void* const* d_in, const int* in_sizes, int n_in,
                              void* d_out, int out_size, void* d_ws, size_t ws_size,
                              hipStream_t stream) {
    const float* x  = (const float*)d_in[0];
    const int*   ei = (const int*)d_in[1];
    const float* W1 = (const float*)d_in[2];
    const float* b1 = (const float*)d_in[3];
    const float* W2 = (const float*)d_in[4];
    const float* b2 = (const float*)d_in[5];
    float* out = (float*)d_out;

    int N = in_sizes[0] / F;          // 100000  (< 2^17 for 4B packing)
    int E = in_sizes[1] / 2;          // 1600000
    const int* src = ei;
    const int* dst = ei + E;

    char* p = (char*)d_ws;
    int*      hcount = (int*)p;      p += alup((size_t)PMAX * GMAX * 4);
    float*    dis    = (float*)p;    p += alup((size_t)N * 4);
    int*      offs   = (int*)p;      p += alup((size_t)N * 4);
    int*      binned = (int*)p;      p += alup((size_t)E * 4);
    int*      srcs   = (int*)p;      p += alup((size_t)E * 4);
    _Float16* g      = (_Float16*)p; p += alup((size_t)N * F * 2);
    _Float16* hh     = (_Float16*)p; p += alup((size_t)N * F * 2);
    _Float16* W1h    = (_Float16*)p; p += alup((size_t)F * F * 2);
    _Float16* W2h    = (_Float16*)p; p += alup((size_t)F * F * 2);

    int nP  = (N + NPB - 1) / NPB;             // 196
    const int nBB = (E + BB - 1) / BB;         // 196
    int grid = nBB > nP ? nBB : nP;
    if (grid < 16) grid = 16;                  // W-convert needs 16 blocks
    const int ntiles = (N + 15) / 16;          // 6250
    const int gemm_grid = (ntiles + 3) / 4;
    const int agg_grid = (N + 3) / 4;

    void* cargs[] = {(void*)&src, (void*)&dst, (void*)&E,
                     (void*)&W1, (void*)&W2, (void*)&W1h, (void*)&W2h,
                     (void*)&hcount, (void*)&binned, (void*)&srcs,
                     (void*)&offs, (void*)&dis, (void*)&N, (void*)&nP};
    hipLaunchCooperativeKernel(csr_coop, dim3(grid), dim3(512), cargs, 0, stream);

    // layer 1: h' = (x @ W1.T)*dis (fp16), agg(+b1+lrelu) -> g (fp16)
    gemm_a32<<<gemm_grid, 256, 0, stream>>>(x, W1h, dis, hh, ntiles);
    agg_to_h<<<agg_grid, 256, 0, stream>>>((const half8_t*)hh, dis, b1, srcs,
                                           offs, (half8_t*)g, N, E);
    // layer 2: h' = (g @ W2.T)*dis (fp16), agg(+b2+lrelu) -> d_out (fp32)
    gemm_a16<<<gemm_grid, 256, 0, stream>>>(g, W2h, dis, hh, ntiles);
    agg_to_f<<<agg_grid, 256, 0, stream>>>((const half8_t*)hh, dis, b2, srcs,
                                           offs, out, N, E);
}

// Round 7
// 327.181 us; speedup vs baseline: 1.4336x; 1.4336x over previous
//
#include <hip/hip_runtime.h>

#define F 128
#define NEG_SLOPE 0.01f
#define NPB 512      // nodes per bucket (1<<9)
#define PMAX 256     // max buckets; nP = ceil(N/512) = 196
#define HB 8192      // edges per hist block
#define BB 8192      // edges per bin block
#define CAP 12288    // csr LDS staging capacity (avg 8192 + tail; key-0 << this)

typedef _Float16 half8_t __attribute__((ext_vector_type(8)));
typedef float f32x4 __attribute__((ext_vector_type(4)));

// ---------------- CSR build: two-level bucket sort (r5 structure) ----------------
// Edge records pack to 4B: (dst_local<<17)|src -- dst_local<512 (9b), src<2^17.

__global__ __launch_bounds__(512) void zero_bcnt(int* __restrict__ bcnt,
                                                 int* __restrict__ bcur) {
    int tid = threadIdx.x;
    if (tid < PMAX) bcnt[tid] = 0;
    else bcur[tid - PMAX] = 0;
}

// hist over dst buckets; last 32 blocks instead convert W1/W2 to fp16.
__global__ __launch_bounds__(256) void hist_kernel(const int* __restrict__ dst,
                                                   int* __restrict__ bcnt,
                                                   int E, int nP,
                                                   const float* __restrict__ W1,
                                                   const float* __restrict__ W2,
                                                   _Float16* __restrict__ W1h,
                                                   _Float16* __restrict__ W2h) {
    __shared__ int h[PMAX];
    int tid = threadIdx.x;
    int hb = gridDim.x - 32;
    if (blockIdx.x >= hb) {
        int i = (blockIdx.x - hb) * 256 + tid;    // 0 .. 8191 (2 * 128*128/4)
        const int n4 = F * F / 4;
        const float* in = (i < n4) ? W1 : W2;
        _Float16* out = (i < n4) ? W1h : W2h;
        int j = (i < n4) ? i : i - n4;
        float4 v = ((const float4*)in)[j];
        half8_t hx;  // only low 4 used
        hx[0] = (_Float16)v.x; hx[1] = (_Float16)v.y;
        hx[2] = (_Float16)v.z; hx[3] = (_Float16)v.w;
        *(int2*)&((_Float16*)out)[j * 4] = *(int2*)&hx;
        return;
    }
    if (tid < PMAX) h[tid] = 0;
    __syncthreads();
    int base = blockIdx.x * HB;
    for (int i = tid; i < HB && base + i < E; i += 256)
        atomicAdd(&h[dst[base + i] >> 9], 1);
    __syncthreads();
    if (tid < nP && h[tid]) atomicAdd(&bcnt[tid], h[tid]);
}

// bin: per-block bucket hist + local scan + in-block global scan of bcnt
// + LDS reorder + coalesced run writes.
__global__ __launch_bounds__(256) void bin_kernel(const int* __restrict__ src,
                                                  const int* __restrict__ dst,
                                                  const int* __restrict__ bcnt,
                                                  int* __restrict__ bcur,
                                                  int* __restrict__ bbase,
                                                  int* __restrict__ binned,
                                                  int E, int nP) {
    __shared__ int hist[PMAX];
    __shared__ int lbase[PMAX];
    __shared__ int gbase[PMAX];
    __shared__ int cur[PMAX];
    __shared__ int sa[PMAX];
    __shared__ int sb[PMAX];
    __shared__ int buf[BB];
    __shared__ unsigned char b8[BB];
    int tid = threadIdx.x;
    int base = blockIdx.x * BB;
    int myE = E - base; if (myE > BB) myE = BB;

    hist[tid] = 0;
    __syncthreads();
    for (int i = tid; i < myE; i += 256)
        atomicAdd(&hist[dst[base + i] >> 9], 1);
    __syncthreads();
    // scan A: local hist -> lbase/cur
    {
        int v = (tid < nP) ? hist[tid] : 0;
        int run = v;
        sa[tid] = v;
        __syncthreads();
        for (int off = 1; off < PMAX; off <<= 1) {
            int add = (tid >= off) ? sa[tid - off] : 0;
            __syncthreads();
            run += add;
            sa[tid] = run;
            __syncthreads();
        }
        if (tid < nP) { lbase[tid] = run - v; cur[tid] = run - v; }
    }
    // scan B: global bcnt -> exclusive prefix; alloc via bcur atomics
    {
        int v = (tid < nP) ? bcnt[tid] : 0;
        int run = v;
        sb[tid] = v;
        __syncthreads();
        for (int off = 1; off < PMAX; off <<= 1) {
            int add = (tid >= off) ? sb[tid - off] : 0;
            __syncthreads();
            run += add;
            sb[tid] = run;
            __syncthreads();
        }
        int gexc = run - v;
        if (tid < nP) {
            if (blockIdx.x == 0) bbase[tid] = gexc;
            gbase[tid] = hist[tid] ? gexc + atomicAdd(&bcur[tid], hist[tid]) : 0;
        }
    }
    __syncthreads();
    // reorder into LDS, bucket-contiguous
    for (int i = tid; i < myE; i += 256) {
        int d = dst[base + i], s = src[base + i];
        int b = d >> 9;
        int lp = atomicAdd(&cur[b], 1);
        buf[lp] = ((d & (NPB - 1)) << 17) | s;
        b8[lp] = (unsigned char)b;
    }
    __syncthreads();
    // coalesced run writes
    for (int j = tid; j < myE; j += 256) {
        int b = b8[j];
        binned[gbase[b] + (j - lbase[b])] = buf[j];
    }
}

// one block per bucket (196 blocks): exact CSR + offs + dis
__global__ __launch_bounds__(256) void csr_kernel(const int* __restrict__ binned,
                                                  const int* __restrict__ bcnt,
                                                  const int* __restrict__ bbase,
                                                  int* __restrict__ srcs,
                                                  int* __restrict__ offs,
                                                  float* __restrict__ dis, int N) {
    __shared__ int cnt[NPB];
    __shared__ int tmp[NPB];
    __shared__ int cur[NPB];
    __shared__ int buf[CAP];
    int tid = threadIdx.x;
    int b = blockIdx.x;
    int ebase = bbase[b];
    int count = bcnt[b];
    int lo = b << 9;
    cnt[tid] = 0;
    cnt[tid + 256] = 0;
    __syncthreads();
    for (int j = tid; j < count; j += 256)
        atomicAdd(&cnt[binned[ebase + j] >> 17], 1);
    __syncthreads();
    int j0 = tid, j1 = tid + 256;
    int v0 = cnt[j0], v1 = cnt[j1];
    tmp[j0] = v0; tmp[j1] = v1;
    __syncthreads();
    for (int off = 1; off < NPB; off <<= 1) {
        int t0 = tmp[j0] + (j0 >= off ? tmp[j0 - off] : 0);
        int t1 = tmp[j1] + (j1 >= off ? tmp[j1 - off] : 0);
        __syncthreads();
        tmp[j0] = t0; tmp[j1] = t1;
        __syncthreads();
    }
    int e0 = tmp[j0] - v0, e1 = tmp[j1] - v1;
    cur[j0] = e0; cur[j1] = e1;
    int n0 = lo + j0, n1 = lo + j1;
    if (n0 < N) { offs[n0] = ebase + e0; dis[n0] = rsqrtf((float)v0 + 1.0f); }
    if (n1 < N) { offs[n1] = ebase + e1; dis[n1] = rsqrtf((float)v1 + 1.0f); }
    __syncthreads();
    for (int j = tid; j < count; j += 256) {
        int rec = binned[ebase + j];
        int pos = atomicAdd(&cur[rec >> 17], 1);
        int s = rec & 0x1FFFF;
        if (pos < CAP) buf[pos] = s; else srcs[ebase + pos] = s;
    }
    __syncthreads();
    int lim = count < CAP ? count : CAP;
    for (int j = tid; j < lim; j += 256)
        srcs[ebase + j] = buf[j];
}

// ---------------- GEMM layer 1: hh = (x @ W1.T) * dis[row] ----------------
// Layouts: A[m=lane&15][k=quad*8+j]; B[n=lane&15][k=quad*8+j] (=W[n][k]);
// C/D: col=lane&15, row=quad*4+reg.

__global__ __launch_bounds__(256) void gemm_a32(const float* __restrict__ A,
                                                const _Float16* __restrict__ Wh,
                                                const float* __restrict__ dis,
                                                _Float16* __restrict__ out,
                                                int ntiles) {
    int wave = threadIdx.x >> 6;
    int lane = threadIdx.x & 63;
    int tile = blockIdx.x * 4 + wave;
    if (tile >= ntiles) return;
    int m = lane & 15, quad = lane >> 4;
    const float* arow = A + (size_t)tile * 16 * F;
    half8_t afrag[4];
#pragma unroll
    for (int c = 0; c < 4; ++c) {
        float4 t0 = *(const float4*)&arow[m * F + c * 32 + quad * 8];
        float4 t1 = *(const float4*)&arow[m * F + c * 32 + quad * 8 + 4];
        afrag[c][0] = (_Float16)t0.x; afrag[c][1] = (_Float16)t0.y;
        afrag[c][2] = (_Float16)t0.z; afrag[c][3] = (_Float16)t0.w;
        afrag[c][4] = (_Float16)t1.x; afrag[c][5] = (_Float16)t1.y;
        afrag[c][6] = (_Float16)t1.z; afrag[c][7] = (_Float16)t1.w;
    }
    f32x4 acc[8];
#pragma unroll
    for (int t = 0; t < 8; ++t) acc[t] = (f32x4){0.f, 0.f, 0.f, 0.f};
#pragma unroll
    for (int c = 0; c < 4; ++c) {
#pragma unroll
        for (int t = 0; t < 8; ++t) {
            half8_t bfrag = *(const half8_t*)&Wh[(t * 16 + m) * F + c * 32 + quad * 8];
            acc[t] = __builtin_amdgcn_mfma_f32_16x16x32_f16(afrag[c], bfrag, acc[t],
                                                            0, 0, 0);
        }
    }
    float d[4];
#pragma unroll
    for (int r = 0; r < 4; ++r) d[r] = dis[tile * 16 + quad * 4 + r];
    _Float16* orow = out + (size_t)tile * 16 * F;
#pragma unroll
    for (int t = 0; t < 8; ++t)
#pragma unroll
        for (int r = 0; r < 4; ++r)
            orow[(quad * 4 + r) * F + t * 16 + m] = (_Float16)(acc[t][r] * d[r]);
}

// ---------------- FUSED layer-boundary: agg(layer1) + GEMM(W2) ----------------
// One block per 16-node tile; 4 waves x 4 nodes each run the proven 8-edge
// pipelined gather (agg equilibrium structure from r2/r5). Finished g-rows
// (b1+lrelu, fp16 -- identical rounding to the old g buffer) are dropped
// into LDS directly in MFMA A-fragment layout [c][quad][m] so the GEMM
// phase ds_read_b128 is fully coalesced (16 lanes x 16B contiguous).
// After one __syncthreads, each wave computes 2 of the 8 output-column
// slices (8 MFMAs) and writes layer-2 h' = (g @ W2.T)*dis directly.
// Removes the 51MB g round-trip + one dispatch + boundary serialization.

__global__ __launch_bounds__(256) void agg_gemm16(const half8_t* __restrict__ h8,
                                                  const float* __restrict__ dis,
                                                  const float* __restrict__ bias,
                                                  const _Float16* __restrict__ Wh,
                                                  const int* __restrict__ srcs,
                                                  const int* __restrict__ offs,
                                                  _Float16* __restrict__ out,
                                                  int n, int E) {
    __shared__ _Float16 Af[2048];   // 16 (c,quad) frag groups x 16 rows x half8
    int tile = blockIdx.x;
    int w = threadIdx.x >> 6;
    int lane = threadIdx.x & 63;
    int g = lane >> 4;
    int fo = lane & 15;
    float4 b0 = ((const float4*)bias)[fo * 2];
    float4 b1v = ((const float4*)bias)[fo * 2 + 1];

#pragma unroll
    for (int i = 0; i < 4; ++i) {
        int node = tile * 16 + w * 4 + i;
        int beg = 0, end = 0;
        if (node < n) {
            beg = offs[node];
            end = (node + 1 < n) ? offs[node + 1] : E;
        }
        float di = (node < n) ? dis[node] : 0.f;
        half8_t hv = h8[(size_t)(node < n ? node : 0) * 16 + fo];
        float acc[8];
#pragma unroll
        for (int j = 0; j < 8; ++j) acc[j] = 0.f;
        if (beg < end) {
            int i0 = beg + g, i1 = beg + 4 + g;
            int s0 = srcs[i0 < end ? i0 : beg];
            int s1 = srcs[i1 < end ? i1 : beg];
            float w0 = (i0 < end) ? 1.f : 0.f;
            float w1 = (i1 < end) ? 1.f : 0.f;
            for (int e = beg; e < end; e += 8) {
                int ns0 = s0, ns1 = s1;
                float nw0 = 0.f, nw1 = 0.f;
                if (e + 8 < end) {
                    int j0 = e + 8 + g, j1 = e + 12 + g;
                    ns0 = srcs[j0 < end ? j0 : beg];
                    ns1 = srcs[j1 < end ? j1 : beg];
                    nw0 = (j0 < end) ? 1.f : 0.f;
                    nw1 = (j1 < end) ? 1.f : 0.f;
                }
                half8_t a0 = h8[(size_t)s0 * 16 + fo];
                half8_t a1 = h8[(size_t)s1 * 16 + fo];
#pragma unroll
                for (int j = 0; j < 8; ++j)
                    acc[j] += w0 * (float)a0[j] + w1 * (float)a1[j];
                s0 = ns0; s1 = ns1; w0 = nw0; w1 = nw1;
            }
        }
#pragma unroll
        for (int j = 0; j < 8; ++j) {
            acc[j] += __shfl_xor(acc[j], 16);
            acc[j] += __shfl_xor(acc[j], 32);
        }
        if (lane < 16 && node < n) {
            acc[0] = di * (acc[0] + (float)hv[0]) + b0.x;
            acc[1] = di * (acc[1] + (float)hv[1]) + b0.y;
            acc[2] = di * (acc[2] + (float)hv[2]) + b0.z;
            acc[3] = di * (acc[3] + (float)hv[3]) + b0.w;
            acc[4] = di * (acc[4] + (float)hv[4]) + b1v.x;
            acc[5] = di * (acc[5] + (float)hv[5]) + b1v.y;
            acc[6] = di * (acc[6] + (float)hv[6]) + b1v.z;
            acc[7] = di * (acc[7] + (float)hv[7]) + b1v.w;
            half8_t o;
#pragma unroll
            for (int j = 0; j < 8; ++j) {
                float v = (acc[j] > 0.f) ? acc[j] : acc[j] * NEG_SLOPE;
                o[j] = (_Float16)v;
            }
            // fragment layout: slot (c=fo>>2, quad=fo&3), row w*4+i
            *(half8_t*)&Af[(((fo >> 2) * 4 + (fo & 3)) * 16 + (w * 4 + i)) * 8] = o;
        }
    }
    __syncthreads();

    // GEMM phase: wave w does output-column slices t = 2w, 2w+1
    int m = fo, quad = g;
    half8_t afrag[4];
#pragma unroll
    for (int c = 0; c < 4; ++c)
        afrag[c] = *(const half8_t*)&Af[((c * 4 + quad) * 16 + m) * 8];
    float d[4];
#pragma unroll
    for (int r = 0; r < 4; ++r) {
        int node = tile * 16 + quad * 4 + r;
        d[r] = (node < n) ? dis[node] : 0.f;
    }
#pragma unroll
    for (int s = 0; s < 2; ++s) {
        int t = w * 2 + s;
        f32x4 acc2 = (f32x4){0.f, 0.f, 0.f, 0.f};
#pragma unroll
        for (int c = 0; c < 4; ++c) {
            half8_t bfrag = *(const half8_t*)&Wh[(t * 16 + m) * F + c * 32 + quad * 8];
            acc2 = __builtin_amdgcn_mfma_f32_16x16x32_f16(afrag[c], bfrag, acc2,
                                                          0, 0, 0);
        }
#pragma unroll
        for (int r = 0; r < 4; ++r) {
            int node = tile * 16 + quad * 4 + r;
            if (node < n)
                out[(size_t)node * F + t * 16 + m] = (_Float16)(acc2[r] * d[r]);
        }
    }
}

// ---------------- final aggregation (unchanged best-known) ----------------

#define AGG_BODY(H8)                                                           \
    int node = blockIdx.x * 4 + (threadIdx.x >> 6);                            \
    int lane = threadIdx.x & 63;                                               \
    if (node >= n) return;                                                     \
    int g = lane >> 4;                                                         \
    int fo = lane & 15;                                                        \
    int beg = offs[node];                                                      \
    int end = (node + 1 < n) ? offs[node + 1] : E;                             \
    float di = dis[node];                                                      \
    half8_t hv = H8[(size_t)node * 16 + fo];                                   \
    float4 b0 = ((const float4*)bias)[fo * 2];                                 \
    float4 b1v = ((const float4*)bias)[fo * 2 + 1];                            \
    float acc[8];                                                              \
    _Pragma("unroll") for (int j = 0; j < 8; ++j) acc[j] = 0.f;                \
    if (beg < end) {                                                           \
        int i0 = beg + g, i1 = beg + 4 + g;                                    \
        int s0 = srcs[i0 < end ? i0 : beg];                                    \
        int s1 = srcs[i1 < end ? i1 : beg];                                    \
        float w0 = (i0 < end) ? 1.f : 0.f;                                     \
        float w1 = (i1 < end) ? 1.f : 0.f;                                     \
        for (int e = beg; e < end; e += 8) {                                   \
            int ns0 = s0, ns1 = s1;                                            \
            float nw0 = 0.f, nw1 = 0.f;                                        \
            if (e + 8 < end) {                                                 \
                int j0 = e + 8 + g, j1 = e + 12 + g;                           \
                ns0 = srcs[j0 < end ? j0 : beg];                               \
                ns1 = srcs[j1 < end ? j1 : beg];                               \
                nw0 = (j0 < end) ? 1.f : 0.f;                                  \
                nw1 = (j1 < end) ? 1.f : 0.f;                                  \
            }                                                                  \
            half8_t a0 = H8[(size_t)s0 * 16 + fo];                             \
            half8_t a1 = H8[(size_t)s1 * 16 + fo];                             \
            _Pragma("unroll") for (int j = 0; j < 8; ++j)                      \
                acc[j] += w0 * (float)a0[j] + w1 * (float)a1[j];               \
            s0 = ns0; s1 = ns1; w0 = nw0; w1 = nw1;                            \
        }                                                                      \
    }                                                                          \
    _Pragma("unroll") for (int j = 0; j < 8; ++j) {                            \
        acc[j] += __shfl_xor(acc[j], 16);                                      \
        acc[j] += __shfl_xor(acc[j], 32);                                      \
    }                                                                          \
    if (lane >= 16) return;                                                    \
    acc[0] = di * (acc[0] + (float)hv[0]) + b0.x;                              \
    acc[1] = di * (acc[1] + (float)hv[1]) + b0.y;                              \
    acc[2] = di * (acc[2] + (float)hv[2]) + b0.z;                              \
    acc[3] = di * (acc[3] + (float)hv[3]) + b0.w;                              \
    acc[4] = di * (acc[4] + (float)hv[4]) + b1v.x;                             \
    acc[5] = di * (acc[5] + (float)hv[5]) + b1v.y;                             \
    acc[6] = di * (acc[6] + (float)hv[6]) + b1v.z;                             \
    acc[7] = di * (acc[7] + (float)hv[7]) + b1v.w;                             \
    _Pragma("unroll") for (int j = 0; j < 8; ++j)                              \
        acc[j] = (acc[j] > 0.f) ? acc[j] : acc[j] * NEG_SLOPE;

__global__ __launch_bounds__(256) void agg_to_f(const half8_t* __restrict__ h8,
                                                const float* __restrict__ dis,
                                                const float* __restrict__ bias,
                                                const int* __restrict__ srcs,
                                                const int* __restrict__ offs,
                                                float* __restrict__ out,
                                                int n, int E) {
    AGG_BODY(h8)
    float4 o0 = make_float4(acc[0], acc[1], acc[2], acc[3]);
    float4 o1 = make_float4(acc[4], acc[5], acc[6], acc[7]);
    ((float4*)out)[(size_t)node * 32 + fo * 2] = o0;
    ((float4*)out)[(size_t)node * 32 + fo * 2 + 1] = o1;
}

// ---------------- launch ----------------

static inline size_t alup(size_t x) { return (x + 255) & ~(size_t)255; }

extern "C" void kernel_launch(void* const* d_in, const int* in_sizes, int n_in,
                              void* d_out, int out_size, void* d_ws, size_t ws_size,
                              hipStream_t stream) {
    const float* x  = (const float*)d_in[0];
    const int*   ei = (const int*)d_in[1];
    const float* W1 = (const float*)d_in[2];
    const float* b1 = (const float*)d_in[3];
    const float* W2 = (const float*)d_in[4];
    const float* b2 = (const float*)d_in[5];
    float* out = (float*)d_out;

    const int N = in_sizes[0] / F;    // 100000  (< 2^17 for 4B packing)
    const int E = in_sizes[1] / 2;    // 1600000
    const int* src = ei;
    const int* dst = ei + E;

    char* p = (char*)d_ws;
    int*      bcnt   = (int*)p;      p += alup(PMAX * 4);
    int*      bbase  = (int*)p;      p += alup(PMAX * 4);
    int*      bcur   = (int*)p;      p += alup(PMAX * 4);
    float*    dis    = (float*)p;    p += alup((size_t)N * 4);
    int*      offs   = (int*)p;      p += alup((size_t)N * 4);
    int*      binned = (int*)p;      p += alup((size_t)E * 4);
    int*      srcs   = (int*)p;      p += alup((size_t)E * 4);
    _Float16* g      = (_Float16*)p; p += alup((size_t)N * F * 2);
    _Float16* hh     = (_Float16*)p; p += alup((size_t)N * F * 2);
    _Float16* W1h    = (_Float16*)p; p += alup((size_t)F * F * 2);
    _Float16* W2h    = (_Float16*)p; p += alup((size_t)F * F * 2);

    const int nP = (N + NPB - 1) / NPB;        // 196
    const int ntiles = (N + 15) / 16;          // 6250
    const int gemm_grid = (ntiles + 3) / 4;
    const int agg_grid = (N + 3) / 4;

    zero_bcnt<<<1, 512, 0, stream>>>(bcnt, bcur);
    hist_kernel<<<(E + HB - 1) / HB + 32, 256, 0, stream>>>(dst, bcnt, E, nP,
                                                            W1, W2, W1h, W2h);
    bin_kernel<<<(E + BB - 1) / BB, 256, 0, stream>>>(src, dst, bcnt, bcur,
                                                      bbase, binned, E, nP);
    csr_kernel<<<nP, 256, 0, stream>>>(binned, bcnt, bbase, srcs, offs, dis, N);

    // layer 1 GEMM: hh = (x @ W1.T)*dis (fp16)
    gemm_a32<<<gemm_grid, 256, 0, stream>>>(x, W1h, dis, hh, ntiles);
    // fused layer boundary: agg(hh)+b1+lrelu -> [LDS] -> @W2.T*dis -> g
    agg_gemm16<<<ntiles, 256, 0, stream>>>((const half8_t*)hh, dis, b1, W2h,
                                           srcs, offs, g, N, E);
    // layer 2 aggregation: agg(g)+b2+lrelu -> d_out (fp32)
    agg_to_f<<<agg_grid, 256, 0, stream>>>((const half8_t*)g, dis, b2, srcs,
                                           offs, out, N, E);
}

// Round 8
// 324.575 us; speedup vs baseline: 1.4451x; 1.0080x over previous
//
#include <hip/hip_runtime.h>

#define F 128
#define NEG_SLOPE 0.01f
#define NPB 512      // nodes per bucket (1<<9)
#define PMAX 256     // max buckets; nP = ceil(N/512) = 196
#define HB 8192      // edges per hist block
#define BB 8192      // edges per bin block
#define CAP 12288    // csr LDS staging capacity (avg 8192 + tail; key-0 << this)

typedef _Float16 half8_t __attribute__((ext_vector_type(8)));
typedef float f32x4 __attribute__((ext_vector_type(4)));

// ---------------- CSR build: two-level bucket sort (r5 structure) ----------------
// Edge records pack to 4B: (dst_local<<17)|src -- dst_local<512 (9b), src<2^17.

__global__ __launch_bounds__(512) void zero_bcnt(int* __restrict__ bcnt,
                                                 int* __restrict__ bcur) {
    int tid = threadIdx.x;
    if (tid < PMAX) bcnt[tid] = 0;
    else bcur[tid - PMAX] = 0;
}

// hist over dst buckets; last 32 blocks instead convert W1/W2 to fp16.
__global__ __launch_bounds__(256) void hist_kernel(const int* __restrict__ dst,
                                                   int* __restrict__ bcnt,
                                                   int E, int nP,
                                                   const float* __restrict__ W1,
                                                   const float* __restrict__ W2,
                                                   _Float16* __restrict__ W1h,
                                                   _Float16* __restrict__ W2h) {
    __shared__ int h[PMAX];
    int tid = threadIdx.x;
    int hb = gridDim.x - 32;
    if (blockIdx.x >= hb) {
        int i = (blockIdx.x - hb) * 256 + tid;    // 0 .. 8191 (2 * 128*128/4)
        const int n4 = F * F / 4;
        const float* in = (i < n4) ? W1 : W2;
        _Float16* out = (i < n4) ? W1h : W2h;
        int j = (i < n4) ? i : i - n4;
        float4 v = ((const float4*)in)[j];
        half8_t hx;  // only low 4 used
        hx[0] = (_Float16)v.x; hx[1] = (_Float16)v.y;
        hx[2] = (_Float16)v.z; hx[3] = (_Float16)v.w;
        *(int2*)&((_Float16*)out)[j * 4] = *(int2*)&hx;
        return;
    }
    if (tid < PMAX) h[tid] = 0;
    __syncthreads();
    int base = blockIdx.x * HB;
    for (int i = tid; i < HB && base + i < E; i += 256)
        atomicAdd(&h[dst[base + i] >> 9], 1);
    __syncthreads();
    if (tid < nP && h[tid]) atomicAdd(&bcnt[tid], h[tid]);
}

// bin: per-block bucket hist + local scan + in-block global scan of bcnt
// + LDS reorder + coalesced run writes.
__global__ __launch_bounds__(256) void bin_kernel(const int* __restrict__ src,
                                                  const int* __restrict__ dst,
                                                  const int* __restrict__ bcnt,
                                                  int* __restrict__ bcur,
                                                  int* __restrict__ bbase,
                                                  int* __restrict__ binned,
                                                  int E, int nP) {
    __shared__ int hist[PMAX];
    __shared__ int lbase[PMAX];
    __shared__ int gbase[PMAX];
    __shared__ int cur[PMAX];
    __shared__ int sa[PMAX];
    __shared__ int sb[PMAX];
    __shared__ int buf[BB];
    __shared__ unsigned char b8[BB];
    int tid = threadIdx.x;
    int base = blockIdx.x * BB;
    int myE = E - base; if (myE > BB) myE = BB;

    hist[tid] = 0;
    __syncthreads();
    for (int i = tid; i < myE; i += 256)
        atomicAdd(&hist[dst[base + i] >> 9], 1);
    __syncthreads();
    // scan A: local hist -> lbase/cur
    {
        int v = (tid < nP) ? hist[tid] : 0;
        int run = v;
        sa[tid] = v;
        __syncthreads();
        for (int off = 1; off < PMAX; off <<= 1) {
            int add = (tid >= off) ? sa[tid - off] : 0;
            __syncthreads();
            run += add;
            sa[tid] = run;
            __syncthreads();
        }
        if (tid < nP) { lbase[tid] = run - v; cur[tid] = run - v; }
    }
    // scan B: global bcnt -> exclusive prefix; alloc via bcur atomics
    {
        int v = (tid < nP) ? bcnt[tid] : 0;
        int run = v;
        sb[tid] = v;
        __syncthreads();
        for (int off = 1; off < PMAX; off <<= 1) {
            int add = (tid >= off) ? sb[tid - off] : 0;
            __syncthreads();
            run += add;
            sb[tid] = run;
            __syncthreads();
        }
        int gexc = run - v;
        if (tid < nP) {
            if (blockIdx.x == 0) bbase[tid] = gexc;
            gbase[tid] = hist[tid] ? gexc + atomicAdd(&bcur[tid], hist[tid]) : 0;
        }
    }
    __syncthreads();
    // reorder into LDS, bucket-contiguous
    for (int i = tid; i < myE; i += 256) {
        int d = dst[base + i], s = src[base + i];
        int b = d >> 9;
        int lp = atomicAdd(&cur[b], 1);
        buf[lp] = ((d & (NPB - 1)) << 17) | s;
        b8[lp] = (unsigned char)b;
    }
    __syncthreads();
    // coalesced run writes
    for (int j = tid; j < myE; j += 256) {
        int b = b8[j];
        binned[gbase[b] + (j - lbase[b])] = buf[j];
    }
}

// one block per bucket (196 blocks): exact CSR + offs + dis
__global__ __launch_bounds__(256) void csr_kernel(const int* __restrict__ binned,
                                                  const int* __restrict__ bcnt,
                                                  const int* __restrict__ bbase,
                                                  int* __restrict__ srcs,
                                                  int* __restrict__ offs,
                                                  float* __restrict__ dis, int N) {
    __shared__ int cnt[NPB];
    __shared__ int tmp[NPB];
    __shared__ int cur[NPB];
    __shared__ int buf[CAP];
    int tid = threadIdx.x;
    int b = blockIdx.x;
    int ebase = bbase[b];
    int count = bcnt[b];
    int lo = b << 9;
    cnt[tid] = 0;
    cnt[tid + 256] = 0;
    __syncthreads();
    for (int j = tid; j < count; j += 256)
        atomicAdd(&cnt[binned[ebase + j] >> 17], 1);
    __syncthreads();
    int j0 = tid, j1 = tid + 256;
    int v0 = cnt[j0], v1 = cnt[j1];
    tmp[j0] = v0; tmp[j1] = v1;
    __syncthreads();
    for (int off = 1; off < NPB; off <<= 1) {
        int t0 = tmp[j0] + (j0 >= off ? tmp[j0 - off] : 0);
        int t1 = tmp[j1] + (j1 >= off ? tmp[j1 - off] : 0);
        __syncthreads();
        tmp[j0] = t0; tmp[j1] = t1;
        __syncthreads();
    }
    int e0 = tmp[j0] - v0, e1 = tmp[j1] - v1;
    cur[j0] = e0; cur[j1] = e1;
    int n0 = lo + j0, n1 = lo + j1;
    if (n0 < N) { offs[n0] = ebase + e0; dis[n0] = rsqrtf((float)v0 + 1.0f); }
    if (n1 < N) { offs[n1] = ebase + e1; dis[n1] = rsqrtf((float)v1 + 1.0f); }
    __syncthreads();
    for (int j = tid; j < count; j += 256) {
        int rec = binned[ebase + j];
        int pos = atomicAdd(&cur[rec >> 17], 1);
        int s = rec & 0x1FFFF;
        if (pos < CAP) buf[pos] = s; else srcs[ebase + pos] = s;
    }
    __syncthreads();
    int lim = count < CAP ? count : CAP;
    for (int j = tid; j < lim; j += 256)
        srcs[ebase + j] = buf[j];
}

// ---------------- GEMM layer 1: hh = (x @ W1.T) * dis[row] ----------------
// Layouts: A[m=lane&15][k=quad*8+j]; B[n=lane&15][k=quad*8+j] (=W[n][k]);
// C/D: col=lane&15, row=quad*4+reg.

__global__ __launch_bounds__(256) void gemm_a32(const float* __restrict__ A,
                                                const _Float16* __restrict__ Wh,
                                                const float* __restrict__ dis,
                                                _Float16* __restrict__ out,
                                                int ntiles) {
    int wave = threadIdx.x >> 6;
    int lane = threadIdx.x & 63;
    int tile = blockIdx.x * 4 + wave;
    if (tile >= ntiles) return;
    int m = lane & 15, quad = lane >> 4;
    const float* arow = A + (size_t)tile * 16 * F;
    half8_t afrag[4];
#pragma unroll
    for (int c = 0; c < 4; ++c) {
        float4 t0 = *(const float4*)&arow[m * F + c * 32 + quad * 8];
        float4 t1 = *(const float4*)&arow[m * F + c * 32 + quad * 8 + 4];
        afrag[c][0] = (_Float16)t0.x; afrag[c][1] = (_Float16)t0.y;
        afrag[c][2] = (_Float16)t0.z; afrag[c][3] = (_Float16)t0.w;
        afrag[c][4] = (_Float16)t1.x; afrag[c][5] = (_Float16)t1.y;
        afrag[c][6] = (_Float16)t1.z; afrag[c][7] = (_Float16)t1.w;
    }
    f32x4 acc[8];
#pragma unroll
    for (int t = 0; t < 8; ++t) acc[t] = (f32x4){0.f, 0.f, 0.f, 0.f};
#pragma unroll
    for (int c = 0; c < 4; ++c) {
#pragma unroll
        for (int t = 0; t < 8; ++t) {
            half8_t bfrag = *(const half8_t*)&Wh[(t * 16 + m) * F + c * 32 + quad * 8];
            acc[t] = __builtin_amdgcn_mfma_f32_16x16x32_f16(afrag[c], bfrag, acc[t],
                                                            0, 0, 0);
        }
    }
    float d[4];
#pragma unroll
    for (int r = 0; r < 4; ++r) d[r] = dis[tile * 16 + quad * 4 + r];
    _Float16* orow = out + (size_t)tile * 16 * F;
#pragma unroll
    for (int t = 0; t < 8; ++t)
#pragma unroll
        for (int r = 0; r < 4; ++r)
            orow[(quad * 4 + r) * F + t * 16 + m] = (_Float16)(acc[t][r] * d[r]);
}

// ---------------- FUSED layer-boundary: agg(layer1) + GEMM(W2) ----------------
// r8 restructure of the r7 fusion (which lost 19us to barrier-tail +
// 1.4M LDS bank conflicts from a broken fragment layout):
//  - block = 2 waves, one 16-row MFMA tile per block; each wave gathers
//    8 nodes serially with the proven 8-edge pipeline. ONE 2-wave barrier:
//    tail = max of two 8-node sums (~+7%) instead of max of 16 single
//    nodes (~+60%). 12500 waves keep CU wave-churn for the gather.
//  - LDS is row-major [16][128] with XOR-swizzled 16B-chunk index
//    (chunk' = chunk ^ (row&7)): write = per-row permutation (2 words/bank,
//    free); GEMM read = exactly 8 words/bank = wave64 b128 minimum.
// Removes the 51MB g round-trip + one dispatch, keeps agg throughput.

__global__ __launch_bounds__(128) void agg_gemm16(const half8_t* __restrict__ h8,
                                                  const float* __restrict__ dis,
                                                  const float* __restrict__ bias,
                                                  const _Float16* __restrict__ Wh,
                                                  const int* __restrict__ srcs,
                                                  const int* __restrict__ offs,
                                                  _Float16* __restrict__ out,
                                                  int n, int E) {
    __shared__ _Float16 Af[16 * F];   // 4KB
    int tile = blockIdx.x;
    int w = threadIdx.x >> 6;         // 0..1
    int lane = threadIdx.x & 63;
    int g = lane >> 4;
    int fo = lane & 15;
    float4 b0 = ((const float4*)bias)[fo * 2];
    float4 b1v = ((const float4*)bias)[fo * 2 + 1];

    for (int i = 0; i < 8; ++i) {
        int row = w * 8 + i;
        int node = tile * 16 + row;
        float acc[8];
#pragma unroll
        for (int j = 0; j < 8; ++j) acc[j] = 0.f;
        int beg = 0, end = 0;
        float di = 0.f;
        half8_t hv = {};
        if (node < n) {
            beg = offs[node];
            end = (node + 1 < n) ? offs[node + 1] : E;
            di = dis[node];
            hv = h8[(size_t)node * 16 + fo];
        }
        if (beg < end) {
            int i0 = beg + g, i1 = beg + 4 + g;
            int s0 = srcs[i0 < end ? i0 : beg];
            int s1 = srcs[i1 < end ? i1 : beg];
            float w0 = (i0 < end) ? 1.f : 0.f;
            float w1 = (i1 < end) ? 1.f : 0.f;
            for (int e = beg; e < end; e += 8) {
                int ns0 = s0, ns1 = s1;
                float nw0 = 0.f, nw1 = 0.f;
                if (e + 8 < end) {
                    int j0 = e + 8 + g, j1 = e + 12 + g;
                    ns0 = srcs[j0 < end ? j0 : beg];
                    ns1 = srcs[j1 < end ? j1 : beg];
                    nw0 = (j0 < end) ? 1.f : 0.f;
                    nw1 = (j1 < end) ? 1.f : 0.f;
                }
                half8_t a0 = h8[(size_t)s0 * 16 + fo];
                half8_t a1 = h8[(size_t)s1 * 16 + fo];
#pragma unroll
                for (int j = 0; j < 8; ++j)
                    acc[j] += w0 * (float)a0[j] + w1 * (float)a1[j];
                s0 = ns0; s1 = ns1; w0 = nw0; w1 = nw1;
            }
        }
#pragma unroll
        for (int j = 0; j < 8; ++j) {
            acc[j] += __shfl_xor(acc[j], 16);
            acc[j] += __shfl_xor(acc[j], 32);
        }
        if (lane < 16) {
            half8_t o = {};
            if (node < n) {
                acc[0] = di * (acc[0] + (float)hv[0]) + b0.x;
                acc[1] = di * (acc[1] + (float)hv[1]) + b0.y;
                acc[2] = di * (acc[2] + (float)hv[2]) + b0.z;
                acc[3] = di * (acc[3] + (float)hv[3]) + b0.w;
                acc[4] = di * (acc[4] + (float)hv[4]) + b1v.x;
                acc[5] = di * (acc[5] + (float)hv[5]) + b1v.y;
                acc[6] = di * (acc[6] + (float)hv[6]) + b1v.z;
                acc[7] = di * (acc[7] + (float)hv[7]) + b1v.w;
#pragma unroll
                for (int j = 0; j < 8; ++j) {
                    float v = (acc[j] > 0.f) ? acc[j] : acc[j] * NEG_SLOPE;
                    o[j] = (_Float16)v;
                }
            }
            int cs = fo ^ (row & 7);                 // swizzled chunk
            *(half8_t*)&Af[row * F + cs * 8] = o;
        }
    }
    __syncthreads();

    // GEMM phase: wave w does output-column slices t = 4w .. 4w+3
    int m = fo, quad = g;
    half8_t afrag[4];
#pragma unroll
    for (int c = 0; c < 4; ++c) {
        int j = c * 4 + quad;
        afrag[c] = *(const half8_t*)&Af[m * F + (j ^ (m & 7)) * 8];
    }
    float d[4];
#pragma unroll
    for (int r = 0; r < 4; ++r) {
        int node = tile * 16 + quad * 4 + r;
        d[r] = (node < n) ? dis[node] : 0.f;
    }
#pragma unroll
    for (int s = 0; s < 4; ++s) {
        int t = w * 4 + s;
        f32x4 acc2 = (f32x4){0.f, 0.f, 0.f, 0.f};
#pragma unroll
        for (int c = 0; c < 4; ++c) {
            half8_t bfrag = *(const half8_t*)&Wh[(t * 16 + m) * F + c * 32 + quad * 8];
            acc2 = __builtin_amdgcn_mfma_f32_16x16x32_f16(afrag[c], bfrag, acc2,
                                                          0, 0, 0);
        }
#pragma unroll
        for (int r = 0; r < 4; ++r) {
            int node = tile * 16 + quad * 4 + r;
            if (node < n)
                out[(size_t)node * F + t * 16 + m] = (_Float16)(acc2[r] * d[r]);
        }
    }
}

// ---------------- final aggregation (unchanged best-known) ----------------

#define AGG_BODY(H8)                                                           \
    int node = blockIdx.x * 4 + (threadIdx.x >> 6);                            \
    int lane = threadIdx.x & 63;                                               \
    if (node >= n) return;                                                     \
    int g = lane >> 4;                                                         \
    int fo = lane & 15;                                                        \
    int beg = offs[node];                                                      \
    int end = (node + 1 < n) ? offs[node + 1] : E;                             \
    float di = dis[node];                                                      \
    half8_t hv = H8[(size_t)node * 16 + fo];                                   \
    float4 b0 = ((const float4*)bias)[fo * 2];                                 \
    float4 b1v = ((const float4*)bias)[fo * 2 + 1];                            \
    float acc[8];                                                              \
    _Pragma("unroll") for (int j = 0; j < 8; ++j) acc[j] = 0.f;                \
    if (beg < end) {                                                           \
        int i0 = beg + g, i1 = beg + 4 + g;                                    \
        int s0 = srcs[i0 < end ? i0 : beg];                                    \
        int s1 = srcs[i1 < end ? i1 : beg];                                    \
        float w0 = (i0 < end) ? 1.f : 0.f;                                     \
        float w1 = (i1 < end) ? 1.f : 0.f;                                     \
        for (int e = beg; e < end; e += 8) {                                   \
            int ns0 = s0, ns1 = s1;                                            \
            float nw0 = 0.f, nw1 = 0.f;                                        \
            if (e + 8 < end) {                                                 \
                int j0 = e + 8 + g, j1 = e + 12 + g;                           \
                ns0 = srcs[j0 < end ? j0 : beg];                               \
                ns1 = srcs[j1 < end ? j1 : beg];                               \
                nw0 = (j0 < end) ? 1.f : 0.f;                                  \
                nw1 = (j1 < end) ? 1.f : 0.f;                                  \
            }                                                                  \
            half8_t a0 = H8[(size_t)s0 * 16 + fo];                             \
            half8_t a1 = H8[(size_t)s1 * 16 + fo];                             \
            _Pragma("unroll") for (int j = 0; j < 8; ++j)                      \
                acc[j] += w0 * (float)a0[j] + w1 * (float)a1[j];               \
            s0 = ns0; s1 = ns1; w0 = nw0; w1 = nw1;                            \
        }                                                                      \
    }                                                                          \
    _Pragma("unroll") for (int j = 0; j < 8; ++j) {                            \
        acc[j] += __shfl_xor(acc[j], 16);                                      \
        acc[j] += __shfl_xor(acc[j], 32);                                      \
    }                                                                          \
    if (lane >= 16) return;                                                    \
    acc[0] = di * (acc[0] + (float)hv[0]) + b0.x;                              \
    acc[1] = di * (acc[1] + (float)hv[1]) + b0.y;                              \
    acc[2] = di * (acc[2] + (float)hv[2]) + b0.z;                              \
    acc[3] = di * (acc[3] + (float)hv[3]) + b0.w;                              \
    acc[4] = di * (acc[4] + (float)hv[4]) + b1v.x;                             \
    acc[5] = di * (acc[5] + (float)hv[5]) + b1v.y;                             \
    acc[6] = di * (acc[6] + (float)hv[6]) + b1v.z;                             \
    acc[7] = di * (acc[7] + (float)hv[7]) + b1v.w;                             \
    _Pragma("unroll") for (int j = 0; j < 8; ++j)                              \
        acc[j] = (acc[j] > 0.f) ? acc[j] : acc[j] * NEG_SLOPE;

__global__ __launch_bounds__(256) void agg_to_f(const half8_t* __restrict__ h8,
                                                const float* __restrict__ dis,
                                                const float* __restrict__ bias,
                                                const int* __restrict__ srcs,
                                                const int* __restrict__ offs,
                                                float* __restrict__ out,
                                                int n, int E) {
    AGG_BODY(h8)
    float4 o0 = make_float4(acc[0], acc[1], acc[2], acc[3]);
    float4 o1 = make_float4(acc[4], acc[5], acc[6], acc[7]);
    ((float4*)out)[(size_t)node * 32 + fo * 2] = o0;
    ((float4*)out)[(size_t)node * 32 + fo * 2 + 1] = o1;
}

// ---------------- launch ----------------

static inline size_t alup(size_t x) { return (x + 255) & ~(size_t)255; }

extern "C" void kernel_launch(void* const* d_in, const int* in_sizes, int n_in,
                              void* d_out, int out_size, void* d_ws, size_t ws_size,
                              hipStream_t stream) {
    const float* x  = (const float*)d_in[0];
    const int*   ei = (const int*)d_in[1];
    const float* W1 = (const float*)d_in[2];
    const float* b1 = (const float*)d_in[3];
    const float* W2 = (const float*)d_in[4];
    const float* b2 = (const float*)d_in[5];
    float* out = (float*)d_out;

    const int N = in_sizes[0] / F;    // 100000  (< 2^17 for 4B packing)
    const int E = in_sizes[1] / 2;    // 1600000
    const int* src = ei;
    const int* dst = ei + E;

    char* p = (char*)d_ws;
    int*      bcnt   = (int*)p;      p += alup(PMAX * 4);
    int*      bbase  = (int*)p;      p += alup(PMAX * 4);
    int*      bcur   = (int*)p;      p += alup(PMAX * 4);
    float*    dis    = (float*)p;    p += alup((size_t)N * 4);
    int*      offs   = (int*)p;      p += alup((size_t)N * 4);
    int*      binned = (int*)p;      p += alup((size_t)E * 4);
    int*      srcs   = (int*)p;      p += alup((size_t)E * 4);
    _Float16* g      = (_Float16*)p; p += alup((size_t)N * F * 2);
    _Float16* hh     = (_Float16*)p; p += alup((size_t)N * F * 2);
    _Float16* W1h    = (_Float16*)p; p += alup((size_t)F * F * 2);
    _Float16* W2h    = (_Float16*)p; p += alup((size_t)F * F * 2);

    const int nP = (N + NPB - 1) / NPB;        // 196
    const int ntiles = (N + 15) / 16;          // 6250
    const int gemm_grid = (ntiles + 3) / 4;
    const int agg_grid = (N + 3) / 4;

    zero_bcnt<<<1, 512, 0, stream>>>(bcnt, bcur);
    hist_kernel<<<(E + HB - 1) / HB + 32, 256, 0, stream>>>(dst, bcnt, E, nP,
                                                            W1, W2, W1h, W2h);
    bin_kernel<<<(E + BB - 1) / BB, 256, 0, stream>>>(src, dst, bcnt, bcur,
                                                      bbase, binned, E, nP);
    csr_kernel<<<nP, 256, 0, stream>>>(binned, bcnt, bbase, srcs, offs, dis, N);

    // layer 1 GEMM: hh = (x @ W1.T)*dis (fp16)
    gemm_a32<<<gemm_grid, 256, 0, stream>>>(x, W1h, dis, hh, ntiles);
    // fused layer boundary: agg(hh)+b1+lrelu -> [LDS] -> @W2.T*dis -> g
    agg_gemm16<<<ntiles, 128, 0, stream>>>((const half8_t*)hh, dis, b1, W2h,
                                           srcs, offs, g, N, E);
    // layer 2 aggregation: agg(g)+b2+lrelu -> d_out (fp32)
    agg_to_f<<<agg_grid, 256, 0, stream>>>((const half8_t*)g, dis, b2, srcs,
                                           offs, out, N, E);
}